// Round 8
// baseline (161.142 us; speedup 1.0000x reference)
//
#include <hip/hip_runtime.h>
#include <hip/hip_bf16.h>

// Problem constants
#define B_  4096
#define T_  80
#define E_  100
#define U_  64
#define G_  256    // 4*U
#define V_  10000

#define S_H  72    // hbuf row stride (bf16 elems), 144B rows (16B aligned)

typedef __attribute__((ext_vector_type(8))) __bf16 bf16x8;
typedef __attribute__((ext_vector_type(4))) __bf16 bf16x4;
typedef __attribute__((ext_vector_type(4))) float  floatx4;

__device__ __forceinline__ float sigmoidf_(float x) {
    return __fdividef(1.f, 1.f + __expf(-x));
}

__device__ __forceinline__ float tanhf_(float x) {
    // 1 - 2/(e^{2x}+1): monotone, saturates correctly, no NaN
    return 1.f - __fdividef(2.f, __expf(2.f * x) + 1.f);
}

// Barrier that waits ONLY on LDS ops (lgkmcnt), NOT vmem: global prefetch
// loads stay in flight across the barrier. Safe here because the only
// cross-wave data (h, tokens) lives in LDS, and lgkmcnt(0) covers both the
// ds_write (producer) and ds_read (WAR on the double buffer) before the wave
// crosses. The "memory" clobber pins LDS op ordering around the barrier.
__device__ __forceinline__ void lds_barrier_() {
    asm volatile("s_waitcnt lgkmcnt(0)\n\ts_barrier" ::: "memory");
}

// ---------------------------------------------------------------------------
// Kernel A (MFMA, LDS-free): embk[v][g] = b1[g] + emb[v] . k1[:,g]
// Grid = (10000/16) x 2 = 1250 blocks x 256 thr. Block: 16 vocab rows x 128
// cols. A-fragments loaded DIRECTLY from emb (lane (n,kg) reads 8 consecutive
// floats of row v0+n -> two float4, cvt to bf16). K padded 100->128 with
// zeros. B-frags from k1 columns; bias in C-init. 10000%16==0: no bounds.
// ---------------------------------------------------------------------------
__global__ __launch_bounds__(256) void embk_kernel(const float* __restrict__ emb,
                                                   const float* __restrict__ k1,
                                                   const float* __restrict__ b1,
                                                   float* __restrict__ embk) {
    const int tid  = threadIdx.x;
    const int lane = tid & 63;
    const int w    = tid >> 6;               // wave: cols n0 + w*32 + [0,32)
    const int n    = lane & 15;
    const int kg   = lane >> 4;
    const int v0   = (blockIdx.x >> 1) * 16;
    const int n0   = (blockIdx.x & 1) * 128;

    // A-fragments: A[m=n][k = kc*32 + kg*8 + jj], row v0+n of emb
    const float* erow = emb + (long)(v0 + n) * E_ + kg * 8;
    bf16x8 afr[4];
#pragma unroll
    for (int kc = 0; kc < 3; ++kc) {         // k = kc*32+kg*8+jj <= 95 < 100
        float4 e0 = *(const float4*)(erow + kc * 32);
        float4 e1 = *(const float4*)(erow + kc * 32 + 4);
        bf16x8 s;
        s[0] = (__bf16)e0.x; s[1] = (__bf16)e0.y; s[2] = (__bf16)e0.z; s[3] = (__bf16)e0.w;
        s[4] = (__bf16)e1.x; s[5] = (__bf16)e1.y; s[6] = (__bf16)e1.z; s[7] = (__bf16)e1.w;
        afr[kc] = s;
    }
    {                                        // kc=3: k = 96 + kg*8 + jj
        bf16x8 s;
#pragma unroll
        for (int jj = 0; jj < 8; ++jj) s[jj] = (__bf16)0.f;
        if (kg == 0) {
            float4 e0 = *(const float4*)(erow + 96);   // k = 96..99
            s[0] = (__bf16)e0.x; s[1] = (__bf16)e0.y; s[2] = (__bf16)e0.z; s[3] = (__bf16)e0.w;
        }
        afr[3] = s;
    }

    // B-fragments: B[k][col], col = n0 + w*32 + ct*16 + n
    bf16x8 bfr[2][4];
#pragma unroll
    for (int ct = 0; ct < 2; ++ct)
#pragma unroll
        for (int kc = 0; kc < 4; ++kc) {
            bf16x8 s;
#pragma unroll
            for (int jj = 0; jj < 8; ++jj) {
                int k = kc * 32 + kg * 8 + jj;
                s[jj] = (k < E_) ? (__bf16)k1[k * G_ + n0 + w * 32 + ct * 16 + n]
                                 : (__bf16)0.f;
            }
            bfr[ct][kc] = s;
        }

#pragma unroll
    for (int ct = 0; ct < 2; ++ct) {
        float bv = b1[n0 + w * 32 + ct * 16 + n];
        floatx4 acc = {bv, bv, bv, bv};
        acc = __builtin_amdgcn_mfma_f32_16x16x32_bf16(afr[0], bfr[ct][0], acc, 0, 0, 0);
        acc = __builtin_amdgcn_mfma_f32_16x16x32_bf16(afr[1], bfr[ct][1], acc, 0, 0, 0);
        acc = __builtin_amdgcn_mfma_f32_16x16x32_bf16(afr[2], bfr[ct][2], acc, 0, 0, 0);
        acc = __builtin_amdgcn_mfma_f32_16x16x32_bf16(afr[3], bfr[ct][3], acc, 0, 0, 0);
        // C/D: row = kg*4 + r, col = n
#pragma unroll
        for (int r = 0; r < 4; ++r)
            embk[(long)(v0 + kg * 4 + r) * G_ + n0 + w * 32 + ct * 16 + n] = acc[r];
    }
}

// ---------------------------------------------------------------------------
// Kernel B: recurrence via transposed MFMA z^T = r1^T @ h^T (R6 structure)
// with the vmcnt-free LDS barrier: xk gathers prefetched 2 steps ahead stay
// in flight ACROSS barriers; compiler's vmcnt wait lands at the C-init use
// two steps later. 256 blocks x 256 thr (4 waves). 4 dense cells/lane.
// ---------------------------------------------------------------------------
__global__ __launch_bounds__(256) void lstm_kernel(const int*   __restrict__ tokens,
                                                   const float* __restrict__ embk,
                                                   const float* __restrict__ r1,
                                                   const float* __restrict__ Wd,
                                                   const float* __restrict__ bd,
                                                   float* __restrict__ out) {
    __shared__ int    tokLDS[16 * T_];       // 5.12 KB
    __shared__ __bf16 hbuf[2][16 * S_H];     // 4.6 KB

    const int tid  = threadIdx.x;
    const int lane = tid & 63;
    const int w    = tid >> 6;               // unit block [w*16, w*16+16)
    const int n    = lane & 15;              // batch row (N-operand of MFMA)
    const int kg   = lane >> 4;              // 0..3
    const int bb   = blockIdx.x * 16;

    for (int i = tid; i < 16 * T_; i += 256) tokLDS[i] = tokens[bb * T_ + i];
    for (int i = tid; i < 2 * 16 * S_H; i += 256) (&hbuf[0][0])[i] = (__bf16)0.f;

    // A-fragments = r1^T (static): tile ct covers gate-cols ct*64 + w*16 + m,
    // A[m][k] = r1[k][ct*64 + w*16 + m]; lane holds m = n, k = kc*32 + kg*8 + jj
    bf16x8 afr[4][2];
#pragma unroll
    for (int ct = 0; ct < 4; ++ct)
#pragma unroll
        for (int kc = 0; kc < 2; ++kc) {
            bf16x8 s;
#pragma unroll
            for (int jj = 0; jj < 8; ++jj)
                s[jj] = (__bf16)r1[(kc * 32 + kg * 8 + jj) * G_ + ct * 64 + w * 16 + n];
            afr[ct][kc] = s;
        }

    // cell state: 4 cells/lane: (row n, unit w*16 + 4*kg + r)
    float c[4] = {0.f, 0.f, 0.f, 0.f};

    __syncthreads();                         // tokens + zeroed hbuf visible

    // xk prefetch, 2 steps deep: xkb[s][ct] = embk[tok[n][s]][ct*64 + w*16 + 4kg ..+3]
    floatx4 xkb[2][4];
#pragma unroll
    for (int s = 0; s < 2; ++s) {
        const float* base = embk + (long)tokLDS[n * T_ + s] * G_ + w * 16 + kg * 4;
#pragma unroll
        for (int ct = 0; ct < 4; ++ct)
            xkb[s][ct] = *(const floatx4*)(base + ct * 64);
    }

    auto step = [&](int t, int sel) {        // sel = t & 1 (constant at call site)
        // B-fragments = h^T_{t-1}: B[k][n] = h[n][k]
        const __bf16* hb = hbuf[sel ^ 1];
        bf16x8 b0 = *(const bf16x8*)(hb + n * S_H + kg * 8);
        bf16x8 b1 = *(const bf16x8*)(hb + n * S_H + 32 + kg * 8);

        // z^T tiles: acc[ct] = r1^T @ h^T + xk  (C-init = prefetched xk)
        floatx4 acc[4];
#pragma unroll
        for (int ct = 0; ct < 4; ++ct) {
            floatx4 a = xkb[sel][ct];
            a = __builtin_amdgcn_mfma_f32_16x16x32_bf16(afr[ct][0], b0, a, 0, 0, 0);
            a = __builtin_amdgcn_mfma_f32_16x16x32_bf16(afr[ct][1], b1, a, 0, 0, 0);
            acc[ct] = a;
        }

        // prefetch xk for t+2 into the slot just consumed; these loads now
        // stay in flight across the next TWO lds_barriers (no vmcnt drain)
        if (t + 2 < T_) {
            const float* base = embk + (long)tokLDS[n * T_ + t + 2] * G_ + w * 16 + kg * 4;
#pragma unroll
            for (int ct = 0; ct < 4; ++ct)
                xkb[sel][ct] = *(const floatx4*)(base + ct * 64);
        }

        // gates: 4 dense cells/lane; acc[0]=i, acc[1]=f, acc[2]=g, acc[3]=o
        bf16x4 hv;
#pragma unroll
        for (int r = 0; r < 4; ++r) {
            float zi = acc[0][r], zf = acc[1][r], zg = acc[2][r], zo = acc[3][r];
            float cn = sigmoidf_(zf) * c[r] + sigmoidf_(zi) * tanhf_(zg);
            float hn = sigmoidf_(zo) * tanhf_(cn);
            c[r] = cn;
            hv[r] = (__bf16)hn;
        }
        // h_new: 4 consecutive units -> one b64 write
        *(bf16x4*)(&hbuf[sel][0] + n * S_H + w * 16 + kg * 4) = hv;

        lds_barrier_();                      // lgkmcnt-only barrier (see above)
    };

    for (int t = 0; t < T_; t += 2) {
        step(t,     0);
        step(t + 1, 1);
    }

    // out[b] = sigmoid(h_final[b] . Wd + bd); h_79 in hbuf[1]
    if (tid < 16) {
        const __bf16* hb = hbuf[1] + tid * S_H;
        float s = bd[0];
#pragma unroll
        for (int u = 0; u < U_; ++u) s = fmaf((float)hb[u], Wd[u], s);
        out[bb + tid] = sigmoidf_(s);
    }
}

// ---------------------------------------------------------------------------
extern "C" void kernel_launch(void* const* d_in, const int* in_sizes, int n_in,
                              void* d_out, int out_size, void* d_ws, size_t ws_size,
                              hipStream_t stream) {
    const int*   tokens = (const int*)  d_in[0];
    const float* emb    = (const float*)d_in[1];
    // d_in[2..4] = k0, r0, b0 : dead in the reference (cell0 state unused)
    const float* k1     = (const float*)d_in[5];
    const float* r1     = (const float*)d_in[6];
    const float* b1     = (const float*)d_in[7];
    const float* Wd     = (const float*)d_in[8];
    const float* bd     = (const float*)d_in[9];
    float*       out    = (float*)d_out;

    float* embk = (float*)d_ws;              // V_*G_ floats = 10.24 MB

    embk_kernel<<<(V_ / 16) * 2, 256, 0, stream>>>(emb, k1, b1, embk);
    lstm_kernel<<<B_ / 16, 256, 0, stream>>>(tokens, embk, r1, Wd, bd, out);
}

// Round 9
// 161.012 us; speedup vs baseline: 1.0008x; 1.0008x over previous
//
#include <hip/hip_runtime.h>
#include <hip/hip_bf16.h>

// Problem constants
#define B_  4096
#define T_  80
#define E_  100
#define U_  64
#define G_  256    // 4*U
#define V_  10000

#define S_H  72    // hbuf row stride (bf16 elems), 144B rows (16B aligned)
#define TP   81    // tokLDS row stride (ints): 81 -> 16 distinct banks (17n+t)
#define EK   128   // embbf row stride (bf16): K padded 100->128, 256B rows

typedef __attribute__((ext_vector_type(8))) __bf16 bf16x8;
typedef __attribute__((ext_vector_type(4))) __bf16 bf16x4;
typedef __attribute__((ext_vector_type(4))) float  floatx4;

__device__ __forceinline__ float sigmoidf_(float x) {
    return __fdividef(1.f, 1.f + __expf(-x));
}

__device__ __forceinline__ float tanhf_(float x) {
    // 1 - 2/(e^{2x}+1): monotone, saturates correctly, no NaN
    return 1.f - __fdividef(2.f, __expf(2.f * x) + 1.f);
}

// Barrier that waits ONLY on LDS ops (lgkmcnt), NOT vmem: global prefetch
// loads stay in flight across the barrier. Safe: all cross-wave data (h,
// tokens) lives in LDS and lgkmcnt(0) covers producer writes + WAR reads.
__device__ __forceinline__ void lds_barrier_() {
    asm volatile("s_waitcnt lgkmcnt(0)\n\ts_barrier" ::: "memory");
}

// ---------------------------------------------------------------------------
// Kernel A: embbf[v][0..127] = bf16(emb[v][0..99]), zero-padded to 128.
// Pure streaming convert: 4 MB read, 2.56 MB write. The 2.56 MB bf16 table
// is what the recurrence gathers from -- it fits in a 4 MB per-XCD L2.
// ---------------------------------------------------------------------------
__global__ __launch_bounds__(256) void embbf_kernel(const float* __restrict__ emb,
                                                    __bf16* __restrict__ embbf) {
    const int idx = blockIdx.x * 256 + threadIdx.x;   // over V_*EK
    const int v   = idx >> 7;
    const int col = idx & (EK - 1);
    float x = (col < E_) ? emb[(long)v * E_ + col] : 0.f;
    embbf[idx] = (__bf16)x;
}

// ---------------------------------------------------------------------------
// Kernel B: full recurrence, z^T = k1^T @ x^T + r1^T @ h^T + b1 per step.
// 256 blocks x 256 thr (4 waves). Block = 16 batch rows; wave w owns units
// [w*16, w*16+16). M = gate-cols (ct = gate), N = batch rows. C/D layout
// gives lane (n,kg): batch row n, units w*16+kg*4+r, gates acc[0..3][r]
// -> 4 dense cells/lane, gate math fully in registers, no z LDS traffic.
//   A1 = k1^T frags (64 VGPRs, static)  A2 = r1^T frags (32 VGPRs, static)
//   B1 = x^T: 4 x bf16x8 gathered from the L2-resident 2.56 MB embbf table,
//        prefetched 2 steps ahead (no HBM-miss wall: table fits in L2)
//   B2 = h^T from LDS (2 x ds_read_b128)
//   ONE lgkmcnt-only barrier per step.
// ---------------------------------------------------------------------------
__global__ __launch_bounds__(256, 1) void lstm_kernel(const int*   __restrict__ tokens,
                                                      const __bf16* __restrict__ embbf,
                                                      const float* __restrict__ k1,
                                                      const float* __restrict__ r1,
                                                      const float* __restrict__ b1,
                                                      const float* __restrict__ Wd,
                                                      const float* __restrict__ bd,
                                                      float* __restrict__ out) {
    __shared__ int    tokLDS[16 * TP];       // 5.2 KB (stride 81: conflict-free)
    __shared__ __bf16 hbuf[2][16 * S_H];     // 4.6 KB

    const int tid  = threadIdx.x;
    const int lane = tid & 63;
    const int w    = tid >> 6;               // unit block [w*16, w*16+16)
    const int n    = lane & 15;              // batch row (N-operand)
    const int kg   = lane >> 4;              // 0..3
    const int bb   = blockIdx.x * 16;

    for (int i = tid; i < 16 * T_; i += 256) {
        int r = i / T_, t = i - r * T_;
        tokLDS[r * TP + t] = tokens[bb * T_ + i];
    }
    for (int i = tid; i < 2 * 16 * S_H; i += 256) (&hbuf[0][0])[i] = (__bf16)0.f;

    // A1 = k1^T (static): A[m=n][k] = k1[k][ct*64 + w*16 + n], k = kc*32+kg*8+jj,
    // zero for k >= 100 (matches embbf zero pad)
    bf16x8 akr[4][4];
#pragma unroll
    for (int ct = 0; ct < 4; ++ct)
#pragma unroll
        for (int kc = 0; kc < 4; ++kc) {
            bf16x8 s;
#pragma unroll
            for (int jj = 0; jj < 8; ++jj) {
                int k = kc * 32 + kg * 8 + jj;
                s[jj] = (k < E_) ? (__bf16)k1[k * G_ + ct * 64 + w * 16 + n]
                                 : (__bf16)0.f;
            }
            akr[ct][kc] = s;
        }

    // A2 = r1^T (static): A[m=n][k] = r1[k][ct*64 + w*16 + n], K = 64
    bf16x8 afr[4][2];
#pragma unroll
    for (int ct = 0; ct < 4; ++ct)
#pragma unroll
        for (int kc = 0; kc < 2; ++kc) {
            bf16x8 s;
#pragma unroll
            for (int jj = 0; jj < 8; ++jj)
                s[jj] = (__bf16)r1[(kc * 32 + kg * 8 + jj) * G_ + ct * 64 + w * 16 + n];
            afr[ct][kc] = s;
        }

    // bias per (ct, r): b1[ct*64 + w*16 + kg*4 + r] (C-init)
    floatx4 bias[4];
#pragma unroll
    for (int ct = 0; ct < 4; ++ct)
#pragma unroll
        for (int r = 0; r < 4; ++r)
            bias[ct][r] = b1[ct * 64 + w * 16 + kg * 4 + r];

    // cell state: 4 cells/lane: (row n, unit w*16 + 4*kg + r)
    float c[4] = {0.f, 0.f, 0.f, 0.f};

    __syncthreads();                         // tokens + zeroed hbuf visible

    // x^T prefetch, 2 steps deep: xe[s][kc] = embbf[tok[n][s]][kc*32 + kg*8 ..+7]
    bf16x8 xe[2][4];
#pragma unroll
    for (int s = 0; s < 2; ++s) {
        const __bf16* base = embbf + (long)tokLDS[n * TP + s] * EK + kg * 8;
#pragma unroll
        for (int kc = 0; kc < 4; ++kc)
            xe[s][kc] = *(const bf16x8*)(base + kc * 32);
    }

    auto step = [&](int t, int sel) {        // sel = t & 1 (constant at call site)
        // B2 = h^T_{t-1}: B[k][n] = h[n][k]
        const __bf16* hb = hbuf[sel ^ 1];
        bf16x8 b0 = *(const bf16x8*)(hb + n * S_H + kg * 8);
        bf16x8 b1v = *(const bf16x8*)(hb + n * S_H + 32 + kg * 8);

        // z^T tiles: acc[ct] = b + k1^T @ x^T + r1^T @ h^T
        floatx4 acc[4];
#pragma unroll
        for (int ct = 0; ct < 4; ++ct) {
            floatx4 a = bias[ct];
            a = __builtin_amdgcn_mfma_f32_16x16x32_bf16(akr[ct][0], xe[sel][0], a, 0, 0, 0);
            a = __builtin_amdgcn_mfma_f32_16x16x32_bf16(akr[ct][1], xe[sel][1], a, 0, 0, 0);
            a = __builtin_amdgcn_mfma_f32_16x16x32_bf16(akr[ct][2], xe[sel][2], a, 0, 0, 0);
            a = __builtin_amdgcn_mfma_f32_16x16x32_bf16(akr[ct][3], xe[sel][3], a, 0, 0, 0);
            a = __builtin_amdgcn_mfma_f32_16x16x32_bf16(afr[ct][0], b0,  a, 0, 0, 0);
            a = __builtin_amdgcn_mfma_f32_16x16x32_bf16(afr[ct][1], b1v, a, 0, 0, 0);
            acc[ct] = a;
        }

        // prefetch x for t+2 into the slot just consumed (L2-resident table)
        if (t + 2 < T_) {
            const __bf16* base = embbf + (long)tokLDS[n * TP + t + 2] * EK + kg * 8;
#pragma unroll
            for (int kc = 0; kc < 4; ++kc)
                xe[sel][kc] = *(const bf16x8*)(base + kc * 32);
        }

        // gates: 4 dense cells/lane; acc[0]=i, acc[1]=f, acc[2]=g, acc[3]=o
        bf16x4 hv;
#pragma unroll
        for (int r = 0; r < 4; ++r) {
            float zi = acc[0][r], zf = acc[1][r], zg = acc[2][r], zo = acc[3][r];
            float cn = sigmoidf_(zf) * c[r] + sigmoidf_(zi) * tanhf_(zg);
            float hn = sigmoidf_(zo) * tanhf_(cn);
            c[r] = cn;
            hv[r] = (__bf16)hn;
        }
        // h_new: 4 consecutive units -> one b64 write
        *(bf16x4*)(&hbuf[sel][0] + n * S_H + w * 16 + kg * 4) = hv;

        lds_barrier_();                      // lgkmcnt-only barrier
    };

    for (int t = 0; t < T_; t += 2) {
        step(t,     0);
        step(t + 1, 1);
    }

    // out[b] = sigmoid(h_final[b] . Wd + bd); h_79 in hbuf[1]
    if (tid < 16) {
        const __bf16* hb = hbuf[1] + tid * S_H;
        float s = bd[0];
#pragma unroll
        for (int u = 0; u < U_; ++u) s = fmaf((float)hb[u], Wd[u], s);
        out[bb + tid] = sigmoidf_(s);
    }
}

// ---------------------------------------------------------------------------
extern "C" void kernel_launch(void* const* d_in, const int* in_sizes, int n_in,
                              void* d_out, int out_size, void* d_ws, size_t ws_size,
                              hipStream_t stream) {
    const int*   tokens = (const int*)  d_in[0];
    const float* emb    = (const float*)d_in[1];
    // d_in[2..4] = k0, r0, b0 : dead in the reference (cell0 state unused)
    const float* k1     = (const float*)d_in[5];
    const float* r1     = (const float*)d_in[6];
    const float* b1     = (const float*)d_in[7];
    const float* Wd     = (const float*)d_in[8];
    const float* bd     = (const float*)d_in[9];
    float*       out    = (float*)d_out;

    __bf16* embbf = (__bf16*)d_ws;           // V_*128 bf16 = 2.56 MB (L2-resident)

    embbf_kernel<<<V_ * EK / 256, 256, 0, stream>>>(emb, embbf);
    lstm_kernel<<<B_ / 16, 256, 0, stream>>>(tokens, embbf, k1, r1, b1, Wd, bd, out);
}

// Round 10
// 160.770 us; speedup vs baseline: 1.0023x; 1.0015x over previous
//
#include <hip/hip_runtime.h>
#include <hip/hip_bf16.h>

// Problem constants
#define B_  4096
#define T_  80
#define E_  100
#define U_  64
#define G_  256    // 4*U
#define V_  10000

#define ROWS 8     // batch rows per lstm block -> 512 blocks = 2 blocks/CU
#define S_H  72    // hbuf row stride (bf16), 144B rows (16B aligned)
#define TP   81    // tokLDS row stride (ints)
#define ZR   68    // zw row stride (floats): 272B, 16B aligned
#define AS   136   // embk A-tile LDS stride (bf16)

typedef __attribute__((ext_vector_type(8))) __bf16 bf16x8;
typedef __attribute__((ext_vector_type(4))) __bf16 bf16x4;
typedef __attribute__((ext_vector_type(2))) __bf16 bf16x2;
typedef __attribute__((ext_vector_type(4))) float  floatx4;

__device__ __forceinline__ float sigmoidf_(float x) {
    return __fdividef(1.f, 1.f + __expf(-x));
}

// LSTM cell with shared-rcp fused activations (8 trans instead of 10):
//   sigma(zi)*tanh(zg) and sigma(zo)*tanh(cn) share one v_rcp each.
__device__ __forceinline__ float cell_(float zi, float zf, float zg, float zo,
                                       float& c) {
    float ei = __expf(-zi);
    float eg = __expf(2.f * zg);
    float Ai = 1.f + ei, Bg = 1.f + eg;
    float rig = __builtin_amdgcn_rcpf(Ai * Bg);
    float term1 = (rig * Bg) * fmaf(-2.f, rig * Ai, 1.f);   // sigma(zi)*tanh(zg)
    float sf = __builtin_amdgcn_rcpf(1.f + __expf(-zf));    // sigma(zf)
    float cn = fmaf(sf, c, term1);
    float eo = __expf(-zo);
    float ec = __expf(2.f * cn);
    float Ao = 1.f + eo, Bc = 1.f + ec;
    float roc = __builtin_amdgcn_rcpf(Ao * Bc);
    float hn = (roc * Bc) * fmaf(-2.f, roc * Ao, 1.f);      // sigma(zo)*tanh(cn)
    c = cn;
    return hn;
}

// lgkmcnt-only barrier: global prefetch loads stay in flight across it.
__device__ __forceinline__ void lds_barrier_() {
    asm volatile("s_waitcnt lgkmcnt(0)\n\ts_barrier" ::: "memory");
}

// ---------------------------------------------------------------------------
// Kernel A (MFMA): embk[v][g] = b1[g] + emb[v] . k1[:,g]  (R3 version, ~14us)
// ---------------------------------------------------------------------------
__global__ __launch_bounds__(256) void embk_kernel(const float* __restrict__ emb,
                                                   const float* __restrict__ k1,
                                                   const float* __restrict__ b1,
                                                   float* __restrict__ embk) {
    __shared__ __bf16 aLDS[64 * AS];

    const int tid  = threadIdx.x;
    const int lane = tid & 63;
    const int w    = tid >> 6;
    const int n    = lane & 15;
    const int kg   = lane >> 4;
    const int v0   = blockIdx.x * 64;
    const int nrows = min(64, V_ - v0);

    for (int i = tid; i < 64 * 28; i += 256) {
        int r = i / 28, e = 100 + (i - r * 28);
        aLDS[r * AS + e] = (__bf16)0.f;
    }
    for (int i = tid; i < nrows * E_; i += 256) {
        int r = i / E_, e = i - r * E_;
        aLDS[r * AS + e] = (__bf16)emb[(long)v0 * E_ + i];
    }

    bf16x8 bfr[4][4];
#pragma unroll
    for (int ct = 0; ct < 4; ++ct)
#pragma unroll
        for (int kc = 0; kc < 4; ++kc) {
            bf16x8 s;
#pragma unroll
            for (int jj = 0; jj < 8; ++jj) {
                int k = kc * 32 + kg * 8 + jj;
                s[jj] = (k < E_) ? (__bf16)k1[k * G_ + w * 64 + ct * 16 + n]
                                 : (__bf16)0.f;
            }
            bfr[ct][kc] = s;
        }

    float bv0 = b1[w * 64 +  0 + n];
    float bv1 = b1[w * 64 + 16 + n];
    float bv2 = b1[w * 64 + 32 + n];
    float bv3 = b1[w * 64 + 48 + n];

    __syncthreads();

#pragma unroll
    for (int mt = 0; mt < 4; ++mt) {
        const __bf16* ab = aLDS + (mt * 16 + n) * AS + kg * 8;
        bf16x8 a0 = *(const bf16x8*)(ab + 0 * 32);
        bf16x8 a1 = *(const bf16x8*)(ab + 1 * 32);
        bf16x8 a2 = *(const bf16x8*)(ab + 2 * 32);
        bf16x8 a3 = *(const bf16x8*)(ab + 3 * 32);
#pragma unroll
        for (int ct = 0; ct < 4; ++ct) {
            float bv = (ct == 0) ? bv0 : (ct == 1) ? bv1 : (ct == 2) ? bv2 : bv3;
            floatx4 acc = {bv, bv, bv, bv};
            acc = __builtin_amdgcn_mfma_f32_16x16x32_bf16(a0, bfr[ct][0], acc, 0, 0, 0);
            acc = __builtin_amdgcn_mfma_f32_16x16x32_bf16(a1, bfr[ct][1], acc, 0, 0, 0);
            acc = __builtin_amdgcn_mfma_f32_16x16x32_bf16(a2, bfr[ct][2], acc, 0, 0, 0);
            acc = __builtin_amdgcn_mfma_f32_16x16x32_bf16(a3, bfr[ct][3], acc, 0, 0, 0);
#pragma unroll
            for (int r = 0; r < 4; ++r) {
                int v = v0 + mt * 16 + kg * 4 + r;
                if (v < V_) embk[(long)v * G_ + w * 64 + ct * 16 + n] = acc[r];
            }
        }
    }
}

// ---------------------------------------------------------------------------
// Kernel B: recurrence, 512 blocks x 256 thr (2 blocks/CU). ROWS=8; wave w
// owns units [w*16, w*16+16). Transposed MFMA z^T = r1^T @ h^T + xk (C-init)
// with N=16 (rows 8..15 dead padding, cost-free). Live z (8 rows x 16 units
// x 4 gates per wave) is bounced through WAVE-PRIVATE LDS (intra-wave, no
// barrier) so all 64 lanes do exactly 2 live cells of gate math. Two
// independent blocks per CU overlap each other's barrier/chain stalls.
// ONE lgkmcnt-only block barrier per step.
// ---------------------------------------------------------------------------
__global__ __launch_bounds__(256, 2) void lstm_kernel(const int*   __restrict__ tokens,
                                                      const float* __restrict__ embk,
                                                      const float* __restrict__ r1,
                                                      const float* __restrict__ Wd,
                                                      const float* __restrict__ bd,
                                                      float* __restrict__ out) {
    __shared__ int    tokLDS[ROWS * TP];     // 2.6 KB
    __shared__ __bf16 hbuf[2][16 * S_H];     // 4.6 KB (rows 8..15 stay zero)
    __shared__ float  zw[4][16 * ZR];        // 17.4 KB wave-private z bounce

    const int tid  = threadIdx.x;
    const int lane = tid & 63;
    const int w    = tid >> 6;               // unit block [w*16, w*16+16)
    const int n    = lane & 15;              // MFMA N index (batch row; 8..15 dead)
    const int kg   = lane >> 4;              // 0..3
    const int bb   = blockIdx.x * ROWS;
    const int row8 = n & 7;                  // xk gather row (dup for dead lanes)

    // gate-phase cell assignment: all 64 lanes -> 2 live cells
    const int grow = lane & 7;               // batch row 0..7
    const int u8   = lane >> 3;              // 0..7
    const int gp   = (u8 + grow) & 7;        // swizzled unit-pair (bank spread)
    const int gu   = gp * 2;                 // local unit = gu, gu+1

    for (int i = tid; i < ROWS * T_; i += 256) {
        int r = i / T_, t = i - r * T_;
        tokLDS[r * TP + t] = tokens[bb * T_ + i];
    }
    for (int i = tid; i < 2 * 16 * S_H; i += 256) (&hbuf[0][0])[i] = (__bf16)0.f;

    // A = r1^T fragments (static): A[m=n][k] = r1[k][ct*64 + w*16 + n]
    bf16x8 afr[4][2];
#pragma unroll
    for (int ct = 0; ct < 4; ++ct)
#pragma unroll
        for (int kc = 0; kc < 2; ++kc) {
            bf16x8 s;
#pragma unroll
            for (int jj = 0; jj < 8; ++jj)
                s[jj] = (__bf16)r1[(kc * 32 + kg * 8 + jj) * G_ + ct * 64 + w * 16 + n];
            afr[ct][kc] = s;
        }

    float c0 = 0.f, c1 = 0.f;                // cells (grow, w*16+gu), (grow, w*16+gu+1)

    __syncthreads();                         // tokens + zeroed hbuf visible

    // xk prefetch, 2 steps deep (C-layout per ct)
    floatx4 xkb[2][4];
#pragma unroll
    for (int s = 0; s < 2; ++s) {
        const float* base = embk + (long)tokLDS[row8 * TP + s] * G_ + w * 16 + kg * 4;
#pragma unroll
        for (int ct = 0; ct < 4; ++ct)
            xkb[s][ct] = *(const floatx4*)(base + ct * 64);
    }

    float* zme = zw[w];

    auto step = [&](int t, int sel) {
        // B = h^T_{t-1}
        const __bf16* hb = hbuf[sel ^ 1];
        bf16x8 b0 = *(const bf16x8*)(hb + n * S_H + kg * 8);
        bf16x8 b1 = *(const bf16x8*)(hb + n * S_H + 32 + kg * 8);

        floatx4 acc[4];
#pragma unroll
        for (int ct = 0; ct < 4; ++ct) {
            floatx4 a = xkb[sel][ct];
            a = __builtin_amdgcn_mfma_f32_16x16x32_bf16(afr[ct][0], b0, a, 0, 0, 0);
            a = __builtin_amdgcn_mfma_f32_16x16x32_bf16(afr[ct][1], b1, a, 0, 0, 0);
            acc[ct] = a;
        }

        // prefetch xk for t+2 (branchless clamp)
        {
            const int tt = (t + 2 < T_) ? (t + 2) : (T_ - 1);
            const float* base = embk + (long)tokLDS[row8 * TP + tt] * G_ + w * 16 + kg * 4;
#pragma unroll
            for (int ct = 0; ct < 4; ++ct)
                xkb[sel][ct] = *(const floatx4*)(base + ct * 64);
        }

        // z scatter (wave-private; rows 8..15 are dead garbage, never read)
#pragma unroll
        for (int r = 0; r < 4; ++r) {
            floatx4 v = {acc[0][r], acc[1][r], acc[2][r], acc[3][r]};
            *(floatx4*)(zme + n * ZR + (kg * 4 + r) * 4) = v;
        }
        __builtin_amdgcn_wave_barrier();     // pin write->read order (intra-wave)

        // z gather: 2 live cells/lane
        const float* zc = zme + grow * ZR + gu * 4;
        floatx4 z0 = *(const floatx4*)(zc);
        floatx4 z1 = *(const floatx4*)(zc + 4);

        float hn0 = cell_(z0[0], z0[1], z0[2], z0[3], c0);
        float hn1 = cell_(z1[0], z1[1], z1[2], z1[3], c1);

        bf16x2 hv; hv[0] = (__bf16)hn0; hv[1] = (__bf16)hn1;
        *(bf16x2*)(&hbuf[sel][0] + grow * S_H + w * 16 + gu) = hv;

        lds_barrier_();                      // h_t visible; WAR on hbuf
    };

    for (int t = 0; t < T_; t += 2) {
        step(t,     0);
        step(t + 1, 1);
    }

    // out[b] = sigmoid(h_final[b] . Wd + bd); h_79 in hbuf[1] rows 0..7
    if (tid < ROWS) {
        const __bf16* hb = hbuf[1] + tid * S_H;
        float s = bd[0];
#pragma unroll
        for (int u = 0; u < U_; ++u) s = fmaf((float)hb[u], Wd[u], s);
        out[bb + tid] = sigmoidf_(s);
    }
}

// ---------------------------------------------------------------------------
extern "C" void kernel_launch(void* const* d_in, const int* in_sizes, int n_in,
                              void* d_out, int out_size, void* d_ws, size_t ws_size,
                              hipStream_t stream) {
    const int*   tokens = (const int*)  d_in[0];
    const float* emb    = (const float*)d_in[1];
    // d_in[2..4] = k0, r0, b0 : dead in the reference (cell0 state unused)
    const float* k1     = (const float*)d_in[5];
    const float* r1     = (const float*)d_in[6];
    const float* b1     = (const float*)d_in[7];
    const float* Wd     = (const float*)d_in[8];
    const float* bd     = (const float*)d_in[9];
    float*       out    = (float*)d_out;

    float* embk = (float*)d_ws;              // V_*G_ floats = 10.24 MB

    embk_kernel<<<(V_ + 63) / 64, 256, 0, stream>>>(emb, k1, b1, embk);
    lstm_kernel<<<B_ / ROWS, 256, 0, stream>>>(tokens, embk, r1, Wd, bd, out);
}